// Round 16
// baseline (162.209 us; speedup 1.0000x reference)
//
#include <hip/hip_runtime.h>
#include <math.h>
#include <float.h>

#define NPTS   32768
#define NCODES 8192
#define D      64
#define HWSZ   4096
#define KSPLIT 8
#define NSTAGE 16            // stages per split (64-code tiles)

#define DECAY_F 0.99f
#define OMD_F   ((float)(1.0 - 0.99))
#define EPS_F   1e-5f

typedef __attribute__((ext_vector_type(8)))  short bf16x8;
typedef __attribute__((ext_vector_type(8)))  unsigned short us8;
typedef __attribute__((ext_vector_type(4)))  float f32x4;
typedef __attribute__((ext_vector_type(16))) float f32x16;

// ---- d_out layout (floats) ----
#define ZQ_OFF    0
#define CODES_OFF 2097152
#define NE_OFF    2129920
#define NCS_OFF   2654208
#define NEA_OFF   2662400

// ---- workspace layout (floats) ----
#define WS_PSUM   0         // 64 (psum[0] = sum(cs)); psum[8] used as int rctr
#define WS_ME2    64        // 8192 : natural order (refine)
#define WS_HIST   8256      // 8192 (int)
#define WS_BOFF   16448     // 8192 (int)
#define WS_BOFF2  24640     // 8192 (int)
#define WS_CODES  32832     // 32768 (int)
#define WS_ORDER  65600     // 32768 (int)
#define WS_PMG    98368     // 1048576 : [split][pt]{m1,g1,m2,g2} coalesced
#define WS_EBI    1146944   // 262144 floats: per-sg 16KB tile = plane0(8KB)|plane1(8KB)
#define WS_ZROW   1409088   // 2097152 : z in [pt][dim] layout

__device__ __forceinline__ unsigned short f2bf(float x) {
    unsigned int u = __float_as_uint(x);
    unsigned int r = (u + 0x7fffu + ((u >> 16) & 1u)) >> 16;
    return (unsigned short)r;
}
__device__ __forceinline__ float bf2f(unsigned short b) {
    return __uint_as_float(((unsigned int)b) << 16);
}

// embed -> interleaved bf16 plane tiles (64-code tiles) + me2 + hist=0 + rctr=0.
__global__ __launch_bounds__(256) void k_prep_e(
    const float* __restrict__ embed,
    unsigned short* __restrict__ ebi,
    float* __restrict__ me2, int* __restrict__ hist, int* __restrict__ rctr)
{
    const int tid = threadIdx.x;
    const int c = blockIdx.x * 32 + (tid >> 3);
    const int s = tid & 7;
    const float4 v0 = *(const float4*)(embed + (size_t)c * D + s * 8);
    const float4 v1 = *(const float4*)(embed + (size_t)c * D + s * 8 + 4);
    float x[8] = {v0.x, v0.y, v0.z, v0.w, v1.x, v1.y, v1.z, v1.w};
    float s2 = 0.f;
#pragma unroll
    for (int j = 0; j < 8; ++j) s2 += x[j] * x[j];
    s2 += __shfl_xor(s2, 1);
    s2 += __shfl_xor(s2, 2);
    s2 += __shfl_xor(s2, 4);
    us8 p0, p1;
#pragma unroll
    for (int j = 0; j < 8; ++j) {
        unsigned short a = f2bf(x[j]);
        float r = x[j] - bf2f(a);
        p0[j] = a; p1[j] = f2bf(r);
    }
    const int sg = c >> 6, ci = c & 63;
    unsigned short* tile = ebi + (size_t)sg * 8192;   // 16KB tile
    *(us8*)(tile + s * 512 + ci * 8) = p0;            // plane 0 (8KB)
    *(us8*)(tile + 4096 + s * 512 + ci * 8) = p1;     // plane 1 (8KB)
    if (s == 0) {
        me2[c] = -0.5f * s2;
        hist[c] = 0;
    }
    if (blockIdx.x == 0 && tid == 0) rctr[0] = 0;
}

#define MFMA32 __builtin_amdgcn_mfma_f32_32x32x16_bf16

#define TOP2(nt, g, gi) { \
    bool c1 = (g) > b1m[nt]; \
    bool c2 = (g) > b2m[nt]; \
    b2m[nt] = c1 ? b1m[nt] : (c2 ? (g) : b2m[nt]); \
    b2g[nt] = c1 ? b1g[nt] : (c2 ? (gi) : b2g[nt]); \
    b1m[nt] = c1 ? (g) : b1m[nt]; \
    b1g[nt] = c1 ? (gi) : b1g[nt]; }

// 8-way max shaped for v_max3 fusion
#define GMAX8(a, o) fmaxf(fmaxf(fmaxf(fmaxf(a[o+0], a[o+1]), a[o+2]), \
                                fmaxf(fmaxf(a[o+3], a[o+4]), a[o+5])), \
                          fmaxf(a[o+6], a[o+7]))

// MFMA argmin, 32x32x16, 2-plane bf16, 3 passes (e1z0, e0z1, e0z0).
// (round-14 structure: best measured 84.6-88us, MfmaUtil ~52%)
__global__ __launch_bounds__(256, 3) void k_argmin_mfma(
    const float* __restrict__ z,
    const unsigned short* __restrict__ ebi,
    float* __restrict__ pmg)
{
    __shared__ __align__(16) char ets[2 * 16384];   // double-buffered stage tile

    const int tid = threadIdx.x;
    const int l = tid & 63;
    const int w = tid >> 6;
    const int l31 = l & 31;
    const int hi = l >> 5;
    const int split = blockIdx.x >> 7;     // 0..7
    const int pgrp  = blockIdx.x & 127;    // 0..127
    const int n0    = pgrp * 256;
    const int b     = n0 >> 12;
    const int hw0   = n0 & 4095;
    const int ptw   = n0 + w * 64;

    const char* ebase = (const char*)ebi;
#define ISSUE_STAGE(sg_, buf_) { \
    const char* gsrc_ = ebase + (size_t)(sg_) * 16384; \
    _Pragma("unroll") \
    for (int i_ = 0; i_ < 4; ++i_) { \
        __builtin_amdgcn_global_load_lds( \
            (const __attribute__((address_space(1))) void*)(gsrc_ + i_ * 4096 + w * 1024 + l * 16), \
            (__attribute__((address_space(3))) void*)(ets + (buf_) * 16384 + i_ * 4096 + w * 1024), \
            16, 0, 0); \
    } }

    ISSUE_STAGE(split * NSTAGE, 0)

    // z fragments: 64 pts/wave (2 tiles of 32), 2 planes, 4 K-chunks
    const float* zb = z + (size_t)b * D * HWSZ;
    us8 zf[2][2][4];
#pragma unroll
    for (int nt = 0; nt < 2; ++nt) {
        const int hwp = hw0 + w * 64 + nt * 32 + l31;
#pragma unroll
        for (int kc = 0; kc < 4; ++kc) {
            us8 p0, p1;
#pragma unroll
            for (int j = 0; j < 8; ++j) {
                float x = zb[(size_t)(kc * 16 + hi * 8 + j) * HWSZ + hwp];
                unsigned short a = f2bf(x);
                float r = x - bf2f(a);
                p0[j] = a; p1[j] = f2bf(r);
            }
            zf[nt][0][kc] = p0; zf[nt][1][kc] = p1;
        }
    }

    f32x16 zerov;
#pragma unroll
    for (int r = 0; r < 16; ++r) zerov[r] = 0.f;

    __syncthreads();   // prologue: drains stage-0 DMA

    float b1m[2] = {-FLT_MAX, -FLT_MAX}, b2m[2] = {-FLT_MAX, -FLT_MAX};
    int   b1g[2] = {0, 0},               b2g[2] = {0, 0};

    for (int stg = 0; stg < NSTAGE; ++stg) {
        const int sg = split * NSTAGE + stg;
        if (stg) {
            asm volatile("s_waitcnt vmcnt(0)" ::: "memory");
            __builtin_amdgcn_s_barrier();
            __builtin_amdgcn_sched_barrier(0);
        }
        if (stg + 1 < NSTAGE) ISSUE_STAGE(sg + 1, (stg + 1) & 1)

        const char* bt = ets + (stg & 1) * 16384;

        f32x16 accA0, accA1, accB0, accB1;
#pragma unroll
        for (int kc = 0; kc < 4; ++kc) {
            const size_t offc0 = (size_t)(kc * 2 + hi) * 1024 + (size_t)l31 * 16;
            const size_t offc1 = offc0 + 32 * 16;
            bf16x8 ea0c0 = *(const bf16x8*)(bt + offc0);
            bf16x8 ea1c0 = *(const bf16x8*)(bt + 8192 + offc0);
            bf16x8 ea0c1 = *(const bf16x8*)(bt + offc1);
            bf16x8 ea1c1 = *(const bf16x8*)(bt + 8192 + offc1);
            if (kc == 0) {
                accA0 = MFMA32(ea1c0, (bf16x8)zf[0][0][0], zerov, 0, 0, 0);
                accB0 = MFMA32(ea1c1, (bf16x8)zf[0][0][0], zerov, 0, 0, 0);
                accA1 = MFMA32(ea1c0, (bf16x8)zf[1][0][0], zerov, 0, 0, 0);
                accB1 = MFMA32(ea1c1, (bf16x8)zf[1][0][0], zerov, 0, 0, 0);
            } else {
                accA0 = MFMA32(ea1c0, (bf16x8)zf[0][0][kc], accA0, 0, 0, 0);
                accB0 = MFMA32(ea1c1, (bf16x8)zf[0][0][kc], accB0, 0, 0, 0);
                accA1 = MFMA32(ea1c0, (bf16x8)zf[1][0][kc], accA1, 0, 0, 0);
                accB1 = MFMA32(ea1c1, (bf16x8)zf[1][0][kc], accB1, 0, 0, 0);
            }
            accA0 = MFMA32(ea0c0, (bf16x8)zf[0][1][kc], accA0, 0, 0, 0);
            accB0 = MFMA32(ea0c1, (bf16x8)zf[0][1][kc], accB0, 0, 0, 0);
            accA1 = MFMA32(ea0c0, (bf16x8)zf[1][1][kc], accA1, 0, 0, 0);
            accB1 = MFMA32(ea0c1, (bf16x8)zf[1][1][kc], accB1, 0, 0, 0);
            accA0 = MFMA32(ea0c0, (bf16x8)zf[0][0][kc], accA0, 0, 0, 0);
            accB0 = MFMA32(ea0c1, (bf16x8)zf[0][0][kc], accB0, 0, 0, 0);
            accA1 = MFMA32(ea0c0, (bf16x8)zf[1][0][kc], accA1, 0, 0, 0);
            accB1 = MFMA32(ea0c1, (bf16x8)zf[1][0][kc], accB1, 0, 0, 0);
        }

        {
            const int gb0 = sg * 8 + hi;         // ct = 0
            const int gb1 = sg * 8 + 4 + hi;     // ct = 1
            float a00 = GMAX8(accA0, 0), a01 = GMAX8(accA0, 8);
            float a10 = GMAX8(accA1, 0), a11 = GMAX8(accA1, 8);
            float b00 = GMAX8(accB0, 0), b01 = GMAX8(accB0, 8);
            float b10 = GMAX8(accB1, 0), b11 = GMAX8(accB1, 8);
            TOP2(0, a00, gb0)
            TOP2(0, a01, gb0 + 2)
            TOP2(1, a10, gb0)
            TOP2(1, a11, gb0 + 2)
            TOP2(0, b00, gb1)
            TOP2(0, b01, gb1 + 2)
            TOP2(1, b10, gb1)
            TOP2(1, b11, gb1 + 2)
        }
    }

    // merge hi halves (point pt's codes are split across lanes l31 and l31+32)
#pragma unroll
    for (int nt = 0; nt < 2; ++nt) {
        float o1 = __shfl_xor(b1m[nt], 32); int o1g = __shfl_xor(b1g[nt], 32);
        float o2 = __shfl_xor(b2m[nt], 32); int o2g = __shfl_xor(b2g[nt], 32);
        float n1m, n2m; int n1g, n2g;
        if (o1 > b1m[nt]) {
            n1m = o1; n1g = o1g;
            if (b1m[nt] >= o2) { n2m = b1m[nt]; n2g = b1g[nt]; } else { n2m = o2; n2g = o2g; }
        } else {
            n1m = b1m[nt]; n1g = b1g[nt];
            if (o1 >= b2m[nt]) { n2m = o1; n2g = o1g; } else { n2m = b2m[nt]; n2g = b2g[nt]; }
        }
        b1m[nt] = n1m; b1g[nt] = n1g; b2m[nt] = n2m; b2g[nt] = n2g;
    }
    if (l < 32) {
#pragma unroll
        for (int nt = 0; nt < 2; ++nt) {
            int pt = ptw + nt * 32 + l31;
            float4 v = {b1m[nt], __int_as_float(b1g[nt]), b2m[nt], __int_as_float(b2g[nt])};
            *(float4*)(pmg + ((size_t)split * NPTS + pt) * 4) = v;
        }
    }
}

// decode: group g (1024 groups of 8) -> code j (0..7) within group
__device__ __forceinline__ int grp_code(int g, int j) {
    int base = (g >> 3) * 64 + ((g >> 2) & 1) * 32 + ((g >> 1) & 1) * 16 + (g & 1) * 4;
    return base + (j & 3) + ((j >> 2) & 1) * 8;
}

// Global top-2 group merge + exact fp32 rescore: 16 threads/point, 1 cand each.
// Fused: last block (device-scope counter) performs the hist scan + sum(cs).
__global__ __launch_bounds__(512) void k_refine(
    const float* __restrict__ z, const float* __restrict__ embed,
    const float* __restrict__ me2, const float* __restrict__ pmg,
    const float* __restrict__ cs_in,
    int* __restrict__ codes_i, float* __restrict__ out_codes,
    float* __restrict__ zq, int* __restrict__ hist, float* __restrict__ zrow,
    int* __restrict__ rctr, int* __restrict__ binoff, int* __restrict__ binoff2,
    float* __restrict__ psum)
{
    __shared__ float  xs[64 * 32];    // [dim][pt]
    __shared__ float4 smg[256];       // transposed: [split j][pt]
    __shared__ float  sbm[512];
    __shared__ int    sbi[512];
    __shared__ int    lastflag;
    const int tid = threadIdx.x;
    const int pi = tid & 31, s = tid >> 5;   // s in 0..15
    const int n0 = blockIdx.x * 32;
    const int b = n0 >> 12, hw0 = n0 & 4095;
    const int n = n0 + pi;

    if (tid < 256) {
        float4 v = ((const float4*)pmg)[(size_t)(tid & 7) * NPTS + n0 + (tid >> 3)];
        smg[(tid & 7) * 32 + (tid >> 3)] = v;
    }
    const float* zb = z + (size_t)b * D * HWSZ + hw0;
#pragma unroll
    for (int i = 0; i < 4; ++i) {
        int c = s * 4 + i;
        xs[c * 32 + pi] = zb[(size_t)c * HWSZ + pi];
    }
    __syncthreads();

    // merge 8 splits x (top1, top2) -> global top-2 groups (redundant per s)
    float t1 = -FLT_MAX, t2 = -FLT_MAX; int g1 = 0, g2 = 0;
#pragma unroll
    for (int j = 0; j < 8; ++j) {
        float4 v = smg[j * 32 + pi];
        float m1 = v.x; int a1 = __float_as_int(v.y);
        float m2 = v.z; int a2 = __float_as_int(v.w);
        if (m1 > t1) { t2 = t1; g2 = g1; t1 = m1; g1 = a1; }
        else if (m1 > t2) { t2 = m1; g2 = a1; }
        if (m2 > t1) { t2 = t1; g2 = g1; t1 = m2; g1 = a2; }
        else if (m2 > t2) { t2 = m2; g2 = a2; }
    }

    // one exact candidate per thread: group (s>>3), code (s&7)
    const int ci = grp_code((s < 8) ? g1 : g2, s & 7);
    float4 e[16];
    {
        const float4* er = (const float4*)(embed + (size_t)ci * D);
#pragma unroll
        for (int q = 0; q < 16; ++q) e[q] = er[q];   // all loads in flight first
    }
    float d0 = 0.f, d1 = 0.f, d2 = 0.f, d3 = 0.f;
#pragma unroll
    for (int q = 0; q < 16; ++q) {
        d0 = fmaf(xs[(4 * q + 0) * 32 + pi], e[q].x, d0);
        d1 = fmaf(xs[(4 * q + 1) * 32 + pi], e[q].y, d1);
        d2 = fmaf(xs[(4 * q + 2) * 32 + pi], e[q].z, d2);
        d3 = fmaf(xs[(4 * q + 3) * 32 + pi], e[q].w, d3);
    }
    float m = ((d0 + d1) + (d2 + d3)) + me2[ci];
    sbm[tid] = m; sbi[tid] = ci;
    __syncthreads();

    if (s == 0) {
        float B = sbm[pi]; int I = sbi[pi];
#pragma unroll
        for (int t = 1; t < 16; ++t) {
            float mm = sbm[t * 32 + pi]; int ii = sbi[t * 32 + pi];
            if (mm > B || (mm == B && ii < I)) { B = mm; I = ii; }
        }
        codes_i[n] = I;
        out_codes[n] = (float)I;
        atomicAdd(&hist[I], 1);
        sbi[pi] = I;    // broadcast chosen code
    }
    __syncthreads();
    {
        // z_q: each thread writes 4 dims
        const int I = sbi[pi];
        const float4 ev = *(const float4*)(embed + (size_t)I * D + s * 4);
        size_t zoff = (size_t)b * D * HWSZ + hw0 + pi;
        zq[zoff + (size_t)(s * 4 + 0) * HWSZ] = ev.x;
        zq[zoff + (size_t)(s * 4 + 1) * HWSZ] = ev.y;
        zq[zoff + (size_t)(s * 4 + 2) * HWSZ] = ev.z;
        zq[zoff + (size_t)(s * 4 + 3) * HWSZ] = ev.w;
    }
    if (s < 8) {
        float4 a4 = {xs[(s * 8 + 0) * 32 + pi], xs[(s * 8 + 1) * 32 + pi],
                     xs[(s * 8 + 2) * 32 + pi], xs[(s * 8 + 3) * 32 + pi]};
        float4 b4 = {xs[(s * 8 + 4) * 32 + pi], xs[(s * 8 + 5) * 32 + pi],
                     xs[(s * 8 + 6) * 32 + pi], xs[(s * 8 + 7) * 32 + pi]};
        *(float4*)(zrow + (size_t)n * 64 + s * 8) = a4;
        *(float4*)(zrow + (size_t)n * 64 + s * 8 + 4) = b4;
    }

    // ---- fused scan: last block to finish performs it ----
    __syncthreads();
    if (tid == 0) {
        __threadfence();
        int d = atomicAdd(rctr, 1);
        lastflag = (d == (int)gridDim.x - 1);
    }
    __syncthreads();
    if (!lastflag) return;

    {
        __shared__ int wtot[8];
        __shared__ int wbase[8];
        __shared__ float csw[8];
        const int lane = tid & 63, w = tid >> 6;   // 8 waves
        int v[16]; int ssum = 0;
        float cz = 0.f;
#pragma unroll
        for (int i = 0; i < 16; ++i) {
            v[i] = hist[tid * 16 + i];
            ssum += v[i];
            cz += cs_in[tid * 16 + i];
        }
        int inc = ssum;
#pragma unroll
        for (int off = 1; off < 64; off <<= 1) {
            int t = __shfl_up(inc, off);
            if (lane >= off) inc += t;
        }
        cz += __shfl_xor(cz, 32); cz += __shfl_xor(cz, 16); cz += __shfl_xor(cz, 8);
        cz += __shfl_xor(cz, 4);  cz += __shfl_xor(cz, 2);  cz += __shfl_xor(cz, 1);
        if (lane == 63) wtot[w] = inc;
        if (lane == 0)  csw[w] = cz;
        __syncthreads();
        if (tid == 0) {
            int a = 0;
            float S = 0.f;
#pragma unroll
            for (int i = 0; i < 8; ++i) { int t = wtot[i]; wbase[i] = a; a += t; S += csw[i]; }
            psum[0] = S;
        }
        __syncthreads();
        int excl = wbase[w] + (inc - ssum);
#pragma unroll
        for (int i = 0; i < 16; ++i) {
            binoff[tid * 16 + i] = excl;
            binoff2[tid * 16 + i] = excl;
            excl += v[i];
        }
    }
}

// scatter point ids into code-sorted order
__global__ void k_reorder(const int* __restrict__ codes_i,
                          int* __restrict__ binoff2, int* __restrict__ order)
{
    int n = blockIdx.x * 256 + threadIdx.x;
    int c = codes_i[n];
    int r = atomicAdd(&binoff2[c], 1);
    order[r] = n;
}

// one wave per code: segmented sum over zrow + fused EMA update + normalize
__global__ __launch_bounds__(256) void k_accum(
    const int* __restrict__ hist, const int* __restrict__ binoff,
    const int* __restrict__ order, const float* __restrict__ zrow,
    const float* __restrict__ cs, const float* __restrict__ eavg,
    const float* __restrict__ psum,
    float* __restrict__ out_ncs, float* __restrict__ out_nea, float* __restrict__ out_ne)
{
    int k = blockIdx.x * 4 + (threadIdx.x >> 6);
    int lane = threadIdx.x & 63;
    int cnt = hist[k], base = binoff[k];
    float acc = 0.f;
    for (int i = 0; i < cnt; ++i) {
        int p = order[base + i];
        acc += zrow[(size_t)p * 64 + lane];
    }
    float S = psum[0];
    float n = DECAY_F * S + OMD_F * (float)NPTS;

    float v = cs[k] * DECAY_F + (float)cnt * OMD_F;
    if (lane == 0) out_ncs[k] = v;

    int idx = k * D + lane;
    float ea = eavg[idx] * DECAY_F + acc * OMD_F;
    out_nea[idx] = ea;
    float csm = (v + EPS_F) / (n + (float)NCODES * EPS_F) * n;
    float u = ea / csm;
    float ss = u * u;
    ss += __shfl_xor(ss, 32);
    ss += __shfl_xor(ss, 16);
    ss += __shfl_xor(ss, 8);
    ss += __shfl_xor(ss, 4);
    ss += __shfl_xor(ss, 2);
    ss += __shfl_xor(ss, 1);
    out_ne[idx] = u / sqrtf(ss);
}

extern "C" void kernel_launch(void* const* d_in, const int* in_sizes, int n_in,
                              void* d_out, int out_size, void* d_ws, size_t ws_size,
                              hipStream_t stream) {
    const float* z     = (const float*)d_in[0];
    const float* embed = (const float*)d_in[1];
    const float* cs    = (const float*)d_in[2];
    const float* eavg  = (const float*)d_in[3];

    float* out = (float*)d_out;
    float* zq        = out + ZQ_OFF;
    float* out_codes = out + CODES_OFF;
    float* out_ne    = out + NE_OFF;
    float* out_ncs   = out + NCS_OFF;
    float* out_nea   = out + NEA_OFF;

    float* ws = (float*)d_ws;
    float* psum   = ws + WS_PSUM;
    int*   rctr   = (int*)(ws + WS_PSUM + 8);
    float* me2    = ws + WS_ME2;
    int*   hist   = (int*)(ws + WS_HIST);
    int*   boff   = (int*)(ws + WS_BOFF);
    int*   boff2  = (int*)(ws + WS_BOFF2);
    int*   codesi = (int*)(ws + WS_CODES);
    int*   order  = (int*)(ws + WS_ORDER);
    float* pmg    = ws + WS_PMG;
    float* zrow   = ws + WS_ZROW;
    unsigned short* ebi = (unsigned short*)(ws + WS_EBI);

    k_prep_e<<<NCODES / 32, 256, 0, stream>>>(embed, ebi, me2, hist, rctr);
    k_argmin_mfma<<<128 * KSPLIT, 256, 0, stream>>>(z, ebi, pmg);
    k_refine<<<NPTS / 32, 512, 0, stream>>>(z, embed, me2, pmg, cs,
                                            codesi, out_codes, zq, hist, zrow,
                                            rctr, boff, boff2, psum);
    k_reorder<<<NPTS / 256, 256, 0, stream>>>(codesi, boff2, order);
    k_accum<<<NCODES / 4, 256, 0, stream>>>(hist, boff, order, zrow, cs, eavg, psum,
                                            out_ncs, out_nea, out_ne);
}

// Round 17
// 135.536 us; speedup vs baseline: 1.1968x; 1.1968x over previous
//
#include <hip/hip_runtime.h>
#include <math.h>
#include <float.h>

#define NPTS   32768
#define NCODES 8192
#define D      64
#define HWSZ   4096
#define KSPLIT 8
#define NSTAGE 16            // stages per split (64-code tiles)

#define DECAY_F 0.99f
#define OMD_F   ((float)(1.0 - 0.99))
#define EPS_F   1e-5f

typedef __attribute__((ext_vector_type(8)))  short bf16x8;
typedef __attribute__((ext_vector_type(8)))  unsigned short us8;
typedef __attribute__((ext_vector_type(4)))  float f32x4;
typedef __attribute__((ext_vector_type(16))) float f32x16;

// ---- d_out layout (floats) ----
#define ZQ_OFF    0
#define CODES_OFF 2097152
#define NE_OFF    2129920
#define NCS_OFF   2654208
#define NEA_OFF   2662400

// ---- workspace layout (floats) ----
#define WS_PSUM   0         // 64 (psum[0] = sum(cs))
#define WS_ME2    64        // 8192 : natural order (refine)
#define WS_HIST   8256      // 8192 (int)
#define WS_BOFF   16448     // 8192 (int)
#define WS_BOFF2  24640     // 8192 (int)
#define WS_CODES  32832     // 32768 (int)
#define WS_ORDER  65600     // 32768 (int)
#define WS_PMG    98368     // 1048576 : [split][pt]{m1,g1,m2,g2} coalesced
#define WS_EBI    1146944   // 262144 floats: per-sg 16KB tile = plane0(8KB)|plane1(8KB)
#define WS_ZROW   1409088   // 2097152 : z in [pt][dim] layout

__device__ __forceinline__ unsigned short f2bf(float x) {
    unsigned int u = __float_as_uint(x);
    unsigned int r = (u + 0x7fffu + ((u >> 16) & 1u)) >> 16;
    return (unsigned short)r;
}
__device__ __forceinline__ float bf2f(unsigned short b) {
    return __uint_as_float(((unsigned int)b) << 16);
}

// embed -> interleaved bf16 plane tiles (64-code tiles) + me2 + hist=0.
__global__ __launch_bounds__(256) void k_prep_e(
    const float* __restrict__ embed,
    unsigned short* __restrict__ ebi,
    float* __restrict__ me2, int* __restrict__ hist)
{
    const int tid = threadIdx.x;
    const int c = blockIdx.x * 32 + (tid >> 3);
    const int s = tid & 7;
    const float4 v0 = *(const float4*)(embed + (size_t)c * D + s * 8);
    const float4 v1 = *(const float4*)(embed + (size_t)c * D + s * 8 + 4);
    float x[8] = {v0.x, v0.y, v0.z, v0.w, v1.x, v1.y, v1.z, v1.w};
    float s2 = 0.f;
#pragma unroll
    for (int j = 0; j < 8; ++j) s2 += x[j] * x[j];
    s2 += __shfl_xor(s2, 1);
    s2 += __shfl_xor(s2, 2);
    s2 += __shfl_xor(s2, 4);
    us8 p0, p1;
#pragma unroll
    for (int j = 0; j < 8; ++j) {
        unsigned short a = f2bf(x[j]);
        float r = x[j] - bf2f(a);
        p0[j] = a; p1[j] = f2bf(r);
    }
    const int sg = c >> 6, ci = c & 63;
    unsigned short* tile = ebi + (size_t)sg * 8192;   // 16KB tile
    *(us8*)(tile + s * 512 + ci * 8) = p0;            // plane 0 (8KB)
    *(us8*)(tile + 4096 + s * 512 + ci * 8) = p1;     // plane 1 (8KB)
    if (s == 0) {
        me2[c] = -0.5f * s2;
        hist[c] = 0;
    }
}

#define MFMA32 __builtin_amdgcn_mfma_f32_32x32x16_bf16

#define TOP2(nt, g, gi) { \
    bool c1 = (g) > b1m[nt]; \
    bool c2 = (g) > b2m[nt]; \
    b2m[nt] = c1 ? b1m[nt] : (c2 ? (g) : b2m[nt]); \
    b2g[nt] = c1 ? b1g[nt] : (c2 ? (gi) : b2g[nt]); \
    b1m[nt] = c1 ? (g) : b1m[nt]; \
    b1g[nt] = c1 ? (gi) : b1g[nt]; }

// 8-way max shaped for v_max3 fusion
#define GMAX8(a, o) fmaxf(fmaxf(fmaxf(fmaxf(a[o+0], a[o+1]), a[o+2]), \
                                fmaxf(fmaxf(a[o+3], a[o+4]), a[o+5])), \
                          fmaxf(a[o+6], a[o+7]))

// MFMA argmin, 32x32x16, 2-plane bf16, 3 passes (e1z0, e0z1, e0z0).
// embed rows unit-norm -> me2 rank-irrelevant; chains seeded via zerov C operand.
// Counted-wait barrier scheme (one raw s_barrier/stage, no fresh-DMA drain).
// Best measured configuration (round 14): 84.6-88 us, MfmaUtil ~52%.
__global__ __launch_bounds__(256, 3) void k_argmin_mfma(
    const float* __restrict__ z,
    const unsigned short* __restrict__ ebi,
    float* __restrict__ pmg)
{
    __shared__ __align__(16) char ets[2 * 16384];   // double-buffered stage tile

    const int tid = threadIdx.x;
    const int l = tid & 63;
    const int w = tid >> 6;
    const int l31 = l & 31;
    const int hi = l >> 5;
    const int split = blockIdx.x >> 7;     // 0..7
    const int pgrp  = blockIdx.x & 127;    // 0..127
    const int n0    = pgrp * 256;
    const int b     = n0 >> 12;
    const int hw0   = n0 & 4095;
    const int ptw   = n0 + w * 64;

    const char* ebase = (const char*)ebi;
#define ISSUE_STAGE(sg_, buf_) { \
    const char* gsrc_ = ebase + (size_t)(sg_) * 16384; \
    _Pragma("unroll") \
    for (int i_ = 0; i_ < 4; ++i_) { \
        __builtin_amdgcn_global_load_lds( \
            (const __attribute__((address_space(1))) void*)(gsrc_ + i_ * 4096 + w * 1024 + l * 16), \
            (__attribute__((address_space(3))) void*)(ets + (buf_) * 16384 + i_ * 4096 + w * 1024), \
            16, 0, 0); \
    } }

    ISSUE_STAGE(split * NSTAGE, 0)

    // z fragments: 64 pts/wave (2 tiles of 32), 2 planes, 4 K-chunks
    const float* zb = z + (size_t)b * D * HWSZ;
    us8 zf[2][2][4];
#pragma unroll
    for (int nt = 0; nt < 2; ++nt) {
        const int hwp = hw0 + w * 64 + nt * 32 + l31;
#pragma unroll
        for (int kc = 0; kc < 4; ++kc) {
            us8 p0, p1;
#pragma unroll
            for (int j = 0; j < 8; ++j) {
                float x = zb[(size_t)(kc * 16 + hi * 8 + j) * HWSZ + hwp];
                unsigned short a = f2bf(x);
                float r = x - bf2f(a);
                p0[j] = a; p1[j] = f2bf(r);
            }
            zf[nt][0][kc] = p0; zf[nt][1][kc] = p1;
        }
    }

    f32x16 zerov;
#pragma unroll
    for (int r = 0; r < 16; ++r) zerov[r] = 0.f;

    __syncthreads();   // prologue: drains stage-0 DMA

    float b1m[2] = {-FLT_MAX, -FLT_MAX}, b2m[2] = {-FLT_MAX, -FLT_MAX};
    int   b1g[2] = {0, 0},               b2g[2] = {0, 0};

    for (int stg = 0; stg < NSTAGE; ++stg) {
        const int sg = split * NSTAGE + stg;
        if (stg) {
            // only DMA(stg) (issued a full stage ago) is outstanding -> ~0 wait
            asm volatile("s_waitcnt vmcnt(0)" ::: "memory");
            __builtin_amdgcn_s_barrier();
            __builtin_amdgcn_sched_barrier(0);
        }
        if (stg + 1 < NSTAGE) ISSUE_STAGE(sg + 1, (stg + 1) & 1)

        const char* bt = ets + (stg & 1) * 16384;

        // 4 independent accumulator chains: {ct0,ct1} x {nt0,nt1}
        f32x16 accA0, accA1, accB0, accB1;
#pragma unroll
        for (int kc = 0; kc < 4; ++kc) {
            const size_t offc0 = (size_t)(kc * 2 + hi) * 1024 + (size_t)l31 * 16;
            const size_t offc1 = offc0 + 32 * 16;
            bf16x8 ea0c0 = *(const bf16x8*)(bt + offc0);
            bf16x8 ea1c0 = *(const bf16x8*)(bt + 8192 + offc0);
            bf16x8 ea0c1 = *(const bf16x8*)(bt + offc1);
            bf16x8 ea1c1 = *(const bf16x8*)(bt + 8192 + offc1);
            // pass e1*z0 (cross); kc==0 seeds chains with zerov (no acc-init movs)
            if (kc == 0) {
                accA0 = MFMA32(ea1c0, (bf16x8)zf[0][0][0], zerov, 0, 0, 0);
                accB0 = MFMA32(ea1c1, (bf16x8)zf[0][0][0], zerov, 0, 0, 0);
                accA1 = MFMA32(ea1c0, (bf16x8)zf[1][0][0], zerov, 0, 0, 0);
                accB1 = MFMA32(ea1c1, (bf16x8)zf[1][0][0], zerov, 0, 0, 0);
            } else {
                accA0 = MFMA32(ea1c0, (bf16x8)zf[0][0][kc], accA0, 0, 0, 0);
                accB0 = MFMA32(ea1c1, (bf16x8)zf[0][0][kc], accB0, 0, 0, 0);
                accA1 = MFMA32(ea1c0, (bf16x8)zf[1][0][kc], accA1, 0, 0, 0);
                accB1 = MFMA32(ea1c1, (bf16x8)zf[1][0][kc], accB1, 0, 0, 0);
            }
            // pass e0*z1 (cross)
            accA0 = MFMA32(ea0c0, (bf16x8)zf[0][1][kc], accA0, 0, 0, 0);
            accB0 = MFMA32(ea0c1, (bf16x8)zf[0][1][kc], accB0, 0, 0, 0);
            accA1 = MFMA32(ea0c0, (bf16x8)zf[1][1][kc], accA1, 0, 0, 0);
            accB1 = MFMA32(ea0c1, (bf16x8)zf[1][1][kc], accB1, 0, 0, 0);
            // pass e0*z0 (main)
            accA0 = MFMA32(ea0c0, (bf16x8)zf[0][0][kc], accA0, 0, 0, 0);
            accB0 = MFMA32(ea0c1, (bf16x8)zf[0][0][kc], accB0, 0, 0, 0);
            accA1 = MFMA32(ea0c0, (bf16x8)zf[1][0][kc], accA1, 0, 0, 0);
            accB1 = MFMA32(ea0c1, (bf16x8)zf[1][0][kc], accB1, 0, 0, 0);
        }

        {
            const int gb0 = sg * 8 + hi;         // ct = 0
            const int gb1 = sg * 8 + 4 + hi;     // ct = 1
            float a00 = GMAX8(accA0, 0), a01 = GMAX8(accA0, 8);
            float a10 = GMAX8(accA1, 0), a11 = GMAX8(accA1, 8);
            float b00 = GMAX8(accB0, 0), b01 = GMAX8(accB0, 8);
            float b10 = GMAX8(accB1, 0), b11 = GMAX8(accB1, 8);
            TOP2(0, a00, gb0)
            TOP2(0, a01, gb0 + 2)
            TOP2(1, a10, gb0)
            TOP2(1, a11, gb0 + 2)
            TOP2(0, b00, gb1)
            TOP2(0, b01, gb1 + 2)
            TOP2(1, b10, gb1)
            TOP2(1, b11, gb1 + 2)
        }
        // no trailing barrier: next iteration's top barrier covers WAR
    }

    // merge hi halves (point pt's codes are split across lanes l31 and l31+32)
#pragma unroll
    for (int nt = 0; nt < 2; ++nt) {
        float o1 = __shfl_xor(b1m[nt], 32); int o1g = __shfl_xor(b1g[nt], 32);
        float o2 = __shfl_xor(b2m[nt], 32); int o2g = __shfl_xor(b2g[nt], 32);
        float n1m, n2m; int n1g, n2g;
        if (o1 > b1m[nt]) {
            n1m = o1; n1g = o1g;
            if (b1m[nt] >= o2) { n2m = b1m[nt]; n2g = b1g[nt]; } else { n2m = o2; n2g = o2g; }
        } else {
            n1m = b1m[nt]; n1g = b1g[nt];
            if (o1 >= b2m[nt]) { n2m = o1; n2g = o1g; } else { n2m = b2m[nt]; n2g = b2g[nt]; }
        }
        b1m[nt] = n1m; b1g[nt] = n1g; b2m[nt] = n2m; b2g[nt] = n2g;
    }
    if (l < 32) {
#pragma unroll
        for (int nt = 0; nt < 2; ++nt) {
            int pt = ptw + nt * 32 + l31;
            float4 v = {b1m[nt], __int_as_float(b1g[nt]), b2m[nt], __int_as_float(b2g[nt])};
            *(float4*)(pmg + ((size_t)split * NPTS + pt) * 4) = v;
        }
    }
}

// decode: group g (1024 groups of 8) -> code of subtask s (s in 0..7)
// g = sg*8 + ct*4 + q2*2 + hi ; code = sg*64 + ct*32 + q2*16 + hi*4 + (s&3) + (s>=4)*8
__device__ __forceinline__ int grp_code(int g, int s) {
    int base = (g >> 3) * 64 + ((g >> 2) & 1) * 32 + ((g >> 1) & 1) * 16 + (g & 1) * 4;
    return base + (s & 3) + ((s >> 2) & 1) * 8;
}

// Global top-2 group merge + exact fp32 rescore of 16 candidates (2 per subtask).
__global__ __launch_bounds__(256) void k_refine(
    const float* __restrict__ z, const float* __restrict__ embed,
    const float* __restrict__ me2, const float* __restrict__ pmg,
    int* __restrict__ codes_i, float* __restrict__ out_codes,
    float* __restrict__ zq, int* __restrict__ hist, float* __restrict__ zrow)
{
    __shared__ float  xs[64 * 32];    // [dim][pt]
    __shared__ float4 smg[256];       // transposed: [split j][pt]
    __shared__ float  sbm[256];
    __shared__ int    sbi[256];
    const int tid = threadIdx.x;
    const int pi = tid & 31, s = tid >> 5;
    const int n0 = blockIdx.x * 32;
    const int b = n0 >> 12, hw0 = n0 & 4095;
    const int n = n0 + pi;

    {
        float4 v = ((const float4*)pmg)[(size_t)(tid & 7) * NPTS + n0 + (tid >> 3)];
        smg[(tid & 7) * 32 + (tid >> 3)] = v;
    }
    const float* zb = z + (size_t)b * D * HWSZ + hw0;
#pragma unroll
    for (int i = 0; i < 8; ++i) {
        int c = s * 8 + i;
        xs[c * 32 + pi] = zb[(size_t)c * HWSZ + pi];
    }
    __syncthreads();
    float x[64];
#pragma unroll
    for (int c = 0; c < 64; ++c) x[c] = xs[c * 32 + pi];

    // merge 8 splits x (top1, top2) -> global top-2 groups
    float t1 = -FLT_MAX, t2 = -FLT_MAX; int g1 = 0, g2 = 0;
#pragma unroll
    for (int j = 0; j < 8; ++j) {
        float4 v = smg[j * 32 + pi];
        float m1 = v.x; int a1 = __float_as_int(v.y);
        float m2 = v.z; int a2 = __float_as_int(v.w);
        if (m1 > t1) { t2 = t1; g2 = g1; t1 = m1; g1 = a1; }
        else if (m1 > t2) { t2 = m1; g2 = a1; }
        if (m2 > t1) { t2 = t1; g2 = g1; t1 = m2; g1 = a2; }
        else if (m2 > t2) { t2 = m2; g2 = a2; }
    }

    float bm = -FLT_MAX; int bi = 0x7fffffff;
#pragma unroll
    for (int cset = 0; cset < 2; ++cset) {
        const int ci = grp_code(cset ? g2 : g1, s);
        const float4* er = (const float4*)(embed + (size_t)ci * D);
        float d0 = 0.f, d1 = 0.f, d2 = 0.f, d3 = 0.f;
#pragma unroll
        for (int q = 0; q < 16; ++q) {
            float4 e4 = er[q];
            d0 = fmaf(x[4 * q + 0], e4.x, d0);
            d1 = fmaf(x[4 * q + 1], e4.y, d1);
            d2 = fmaf(x[4 * q + 2], e4.z, d2);
            d3 = fmaf(x[4 * q + 3], e4.w, d3);
        }
        float m = ((d0 + d1) + (d2 + d3)) + me2[ci];
        if (m > bm || (m == bm && ci < bi)) { bm = m; bi = ci; }
    }
    sbm[tid] = bm; sbi[tid] = bi;
    __syncthreads();

    if (s == 0) {
        float B = sbm[pi]; int I = sbi[pi];
#pragma unroll
        for (int t = 1; t < 8; ++t) {
            float mm = sbm[t * 32 + pi]; int ii = sbi[t * 32 + pi];
            if (mm > B || (mm == B && ii < I)) { B = mm; I = ii; }
        }
        codes_i[n] = I;
        out_codes[n] = (float)I;
        atomicAdd(&hist[I], 1);
        sbi[pi] = I;    // broadcast chosen code (column pi, row 0: race-free)
    }
    __syncthreads();
    {
        // all 8 subtasks write 8 dims of z_q each (8x store parallelism)
        const int I = sbi[pi];
        const float* err = embed + (size_t)I * D;
        const float4 e0 = *(const float4*)(err + s * 8);
        const float4 e1 = *(const float4*)(err + s * 8 + 4);
        float ev[8] = {e0.x, e0.y, e0.z, e0.w, e1.x, e1.y, e1.z, e1.w};
        size_t zoff = (size_t)b * D * HWSZ + hw0 + pi;
#pragma unroll
        for (int j = 0; j < 8; ++j)
            zq[zoff + (size_t)(s * 8 + j) * HWSZ] = ev[j];
    }
    {
        float4 a4 = {x[s * 8 + 0], x[s * 8 + 1], x[s * 8 + 2], x[s * 8 + 3]};
        float4 b4 = {x[s * 8 + 4], x[s * 8 + 5], x[s * 8 + 6], x[s * 8 + 7]};
        *(float4*)(zrow + (size_t)n * 64 + s * 8) = a4;
        *(float4*)(zrow + (size_t)n * 64 + s * 8 + 4) = b4;
    }
}

// exclusive prefix sum of hist -> binoff/binoff2 ; also psum[0] = sum(cs)
__global__ __launch_bounds__(1024) void k_scan(
    const int* __restrict__ hist, const float* __restrict__ cs_in,
    int* __restrict__ binoff, int* __restrict__ binoff2, float* __restrict__ psum)
{
    __shared__ int wtot[16];
    __shared__ int wbase[16];
    __shared__ float csw[16];
    const int tid = threadIdx.x;
    const int lane = tid & 63, w = tid >> 6;
    int v[8]; int s = 0;
    float cz = 0.f;
#pragma unroll
    for (int i = 0; i < 8; ++i) {
        v[i] = hist[tid * 8 + i];
        s += v[i];
        cz += cs_in[tid * 8 + i];
    }
    int inc = s;
#pragma unroll
    for (int off = 1; off < 64; off <<= 1) {
        int t = __shfl_up(inc, off);
        if (lane >= off) inc += t;
    }
    cz += __shfl_xor(cz, 32); cz += __shfl_xor(cz, 16); cz += __shfl_xor(cz, 8);
    cz += __shfl_xor(cz, 4);  cz += __shfl_xor(cz, 2);  cz += __shfl_xor(cz, 1);
    if (lane == 63) wtot[w] = inc;
    if (lane == 0)  csw[w] = cz;
    __syncthreads();
    if (tid == 0) {
        int a = 0;
        float S = 0.f;
#pragma unroll
        for (int i = 0; i < 16; ++i) { int t = wtot[i]; wbase[i] = a; a += t; S += csw[i]; }
        psum[0] = S;
    }
    __syncthreads();
    int excl = wbase[w] + (inc - s);
#pragma unroll
    for (int i = 0; i < 8; ++i) {
        binoff[tid * 8 + i] = excl;
        binoff2[tid * 8 + i] = excl;
        excl += v[i];
    }
}

// scatter point ids into code-sorted order
__global__ void k_reorder(const int* __restrict__ codes_i,
                          int* __restrict__ binoff2, int* __restrict__ order)
{
    int n = blockIdx.x * 256 + threadIdx.x;
    int c = codes_i[n];
    int r = atomicAdd(&binoff2[c], 1);
    order[r] = n;
}

// one wave per code: segmented sum over zrow + fused EMA update + normalize
__global__ __launch_bounds__(256) void k_accum(
    const int* __restrict__ hist, const int* __restrict__ binoff,
    const int* __restrict__ order, const float* __restrict__ zrow,
    const float* __restrict__ cs, const float* __restrict__ eavg,
    const float* __restrict__ psum,
    float* __restrict__ out_ncs, float* __restrict__ out_nea, float* __restrict__ out_ne)
{
    int k = blockIdx.x * 4 + (threadIdx.x >> 6);
    int lane = threadIdx.x & 63;
    int cnt = hist[k], base = binoff[k];
    float acc = 0.f;
    for (int i = 0; i < cnt; ++i) {
        int p = order[base + i];
        acc += zrow[(size_t)p * 64 + lane];
    }
    float S = psum[0];
    float n = DECAY_F * S + OMD_F * (float)NPTS;

    float v = cs[k] * DECAY_F + (float)cnt * OMD_F;
    if (lane == 0) out_ncs[k] = v;

    int idx = k * D + lane;
    float ea = eavg[idx] * DECAY_F + acc * OMD_F;
    out_nea[idx] = ea;
    float csm = (v + EPS_F) / (n + (float)NCODES * EPS_F) * n;
    float u = ea / csm;
    float ss = u * u;
    ss += __shfl_xor(ss, 32);
    ss += __shfl_xor(ss, 16);
    ss += __shfl_xor(ss, 8);
    ss += __shfl_xor(ss, 4);
    ss += __shfl_xor(ss, 2);
    ss += __shfl_xor(ss, 1);
    out_ne[idx] = u / sqrtf(ss);
}

extern "C" void kernel_launch(void* const* d_in, const int* in_sizes, int n_in,
                              void* d_out, int out_size, void* d_ws, size_t ws_size,
                              hipStream_t stream) {
    const float* z     = (const float*)d_in[0];
    const float* embed = (const float*)d_in[1];
    const float* cs    = (const float*)d_in[2];
    const float* eavg  = (const float*)d_in[3];

    float* out = (float*)d_out;
    float* zq        = out + ZQ_OFF;
    float* out_codes = out + CODES_OFF;
    float* out_ne    = out + NE_OFF;
    float* out_ncs   = out + NCS_OFF;
    float* out_nea   = out + NEA_OFF;

    float* ws = (float*)d_ws;
    float* psum   = ws + WS_PSUM;
    float* me2    = ws + WS_ME2;
    int*   hist   = (int*)(ws + WS_HIST);
    int*   boff   = (int*)(ws + WS_BOFF);
    int*   boff2  = (int*)(ws + WS_BOFF2);
    int*   codesi = (int*)(ws + WS_CODES);
    int*   order  = (int*)(ws + WS_ORDER);
    float* pmg    = ws + WS_PMG;
    float* zrow   = ws + WS_ZROW;
    unsigned short* ebi = (unsigned short*)(ws + WS_EBI);

    k_prep_e<<<NCODES / 32, 256, 0, stream>>>(embed, ebi, me2, hist);
    k_argmin_mfma<<<128 * KSPLIT, 256, 0, stream>>>(z, ebi, pmg);
    k_refine<<<NPTS / 32, 256, 0, stream>>>(z, embed, me2, pmg,
                                            codesi, out_codes, zq, hist, zrow);
    k_scan<<<1, 1024, 0, stream>>>(hist, cs, boff, boff2, psum);
    k_reorder<<<NPTS / 256, 256, 0, stream>>>(codesi, boff2, order);
    k_accum<<<NCODES / 4, 256, 0, stream>>>(hist, boff, order, zrow, cs, eavg, psum,
                                            out_ncs, out_nea, out_ne);
}